// Round 11
// baseline (473.495 us; speedup 1.0000x reference)
//
#include <hip/hip_runtime.h>
#include <cmath>

namespace {

constexpr int B_ = 2;
constexpr int T_ = 2048;
constexpr int C_ = 1024;
constexpr int H_ = 16;
constexpr int D_ = 64;

typedef _Float16 half8 __attribute__((ext_vector_type(8)));
typedef _Float16 half4 __attribute__((ext_vector_type(4)));
typedef float f32x4 __attribute__((ext_vector_type(4)));

__device__ inline f32x4 vmax4(f32x4 a, f32x4 b) {
  f32x4 r;
  r[0] = fmaxf(a[0], b[0]); r[1] = fmaxf(a[1], b[1]);
  r[2] = fmaxf(a[2], b[2]); r[3] = fmaxf(a[3], b[3]);
  return r;
}

__device__ __forceinline__ void gload16(const _Float16* g, _Float16* l) {
  __builtin_amdgcn_global_load_lds(
      (const __attribute__((address_space(1))) unsigned int*)g,
      (__attribute__((address_space(3))) unsigned int*)l, 16, 0, 0);
}

// LDS-visibility barrier WITHOUT the vmcnt drain of __syncthreads():
// keeps in-flight global_load_lds staging alive across the barrier (T4).
__device__ __forceinline__ void lds_barrier() {
  asm volatile("s_waitcnt lgkmcnt(0)" ::: "memory");
  __builtin_amdgcn_s_barrier();
}

// ---------------------------------------------------------------------------
// Fused cast: 7 fp32 arrays -> f16 (xq,xk,xv: 4M els; Wq,Wk,Wv,Wo: 1M els).
// ---------------------------------------------------------------------------
__global__ __launch_bounds__(256)
void cast7(const float* __restrict__ xq, const float* __restrict__ xk,
           const float* __restrict__ xv, const float* __restrict__ wq,
           const float* __restrict__ wk, const float* __restrict__ wv,
           const float* __restrict__ wo,
           _Float16* __restrict__ dxq, _Float16* __restrict__ dxk,
           _Float16* __restrict__ dxv, _Float16* __restrict__ dwq,
           _Float16* __restrict__ dwk, _Float16* __restrict__ dwv,
           _Float16* __restrict__ dwo) {
  constexpr size_t NX = (size_t)4 << 20;
  constexpr size_t NW = (size_t)1 << 20;
  size_t g = ((size_t)blockIdx.x * 256 + threadIdx.x) * 8;
  const float* s; _Float16* d; size_t off;
  if      (g <     NX)          { s = xq; d = dxq; off = g; }
  else if (g < 2 * NX)          { s = xk; d = dxk; off = g - NX; }
  else if (g < 3 * NX)          { s = xv; d = dxv; off = g - 2 * NX; }
  else if (g < 3 * NX + NW)     { s = wq; d = dwq; off = g - 3 * NX; }
  else if (g < 3 * NX + 2 * NW) { s = wk; d = dwk; off = g - 3 * NX - NW; }
  else if (g < 3 * NX + 3 * NW) { s = wv; d = dwv; off = g - 3 * NX - 2 * NW; }
  else                          { s = wo; d = dwo; off = g - 3 * NX - 3 * NW; }
  const float4 a = *(const float4*)(s + off);
  const float4 b = *(const float4*)(s + off + 4);
  half8 h;
  h[0] = (_Float16)a.x; h[1] = (_Float16)a.y; h[2] = (_Float16)a.z; h[3] = (_Float16)a.w;
  h[4] = (_Float16)b.x; h[5] = (_Float16)b.y; h[6] = (_Float16)b.z; h[7] = (_Float16)b.w;
  *(half8*)(d + off) = h;
}

// ---------------------------------------------------------------------------
// LDS-staged f16 NT GEMM (m97 structure): Y[m][n] = sum_k A[m][k]*W[n][k].
// Tile 128x128, BK=32; 4 waves, each a 64x64 quadrant (4x4 16x16x32 MFMAs).
// mode 0: f16 Y out (z==0 output scaled by qsc: folds sqrt(D) into Q).
// mode 2: fp32 out + bias.
// ---------------------------------------------------------------------------
__global__ __launch_bounds__(256, 3)
void gemm_f16nt(const _Float16* __restrict__ A0, const _Float16* __restrict__ A1,
                const _Float16* __restrict__ A2,
                const _Float16* __restrict__ W0, const _Float16* __restrict__ W1,
                const _Float16* __restrict__ W2,
                _Float16* __restrict__ Y0, _Float16* __restrict__ Y1,
                _Float16* __restrict__ Y2,
                float* __restrict__ Yf, const float* __restrict__ bias,
                int K, int N, int mode, float qsc) {
  __shared__ _Float16 sA[128 * 32];
  __shared__ _Float16 sW[128 * 32];

  const int tid  = threadIdx.x;
  const int lane = tid & 63;
  const int w    = tid >> 6;
  const int l15  = lane & 15;
  const int quad = lane >> 4;
  const int z    = blockIdx.z;
  const _Float16* A = (z == 0) ? A0 : (z == 1) ? A1 : A2;
  const _Float16* W = (z == 0) ? W0 : (z == 1) ? W1 : W2;
  _Float16*       Y = (z == 0) ? Y0 : (z == 1) ? Y1 : Y2;

  const int m0 = blockIdx.y * 128;
  const int n0 = blockIdx.x * 128;

  const int Rb  = lane >> 2;
  const int pch = lane & 3;
  const int lch = pch ^ ((Rb >> 1) & 3);
  const int swr = (l15 >> 1) & 3;

  f32x4 acc[4][4];
#pragma unroll
  for (int mt = 0; mt < 4; ++mt)
#pragma unroll
    for (int nt = 0; nt < 4; ++nt)
      acc[mt][nt] = (f32x4){0.f, 0.f, 0.f, 0.f};

  const int wm = (w >> 1) * 64;
  const int wn = (w & 1) * 64;

  for (int k0 = 0; k0 < K; k0 += 32) {
    __syncthreads();
#pragma unroll
    for (int j = 0; j < 2; ++j) {
      const int seg = w * 32 + j * 16;
      gload16(A + (size_t)(m0 + seg + Rb) * K + k0 + lch * 8, &sA[seg * 32]);
      gload16(W + (size_t)(n0 + seg + Rb) * K + k0 + lch * 8, &sW[seg * 32]);
    }
    __syncthreads();

    half8 af[4], wf[4];
#pragma unroll
    for (int mt = 0; mt < 4; ++mt) {
      const int R = wm + mt * 16 + l15;
      af[mt] = *(const half8*)&sA[R * 32 + (quad ^ swr) * 8];
    }
#pragma unroll
    for (int nt = 0; nt < 4; ++nt) {
      const int R = wn + nt * 16 + l15;
      wf[nt] = *(const half8*)&sW[R * 32 + (quad ^ swr) * 8];
    }
#pragma unroll
    for (int mt = 0; mt < 4; ++mt)
#pragma unroll
      for (int nt = 0; nt < 4; ++nt)
        acc[mt][nt] = __builtin_amdgcn_mfma_f32_16x16x32_f16(wf[nt], af[mt], acc[mt][nt], 0, 0, 0);
  }

  const float ysc = (mode == 0 && z == 0) ? qsc : 1.f;
#pragma unroll
  for (int mt = 0; mt < 4; ++mt)
#pragma unroll
    for (int nt = 0; nt < 4; ++nt) {
      const int m = m0 + wm + mt * 16 + l15;
      const int n = n0 + wn + nt * 16 + quad * 4;
      if (mode == 2) {
        float4 v;
        v.x = acc[mt][nt][0] + bias[n + 0];
        v.y = acc[mt][nt][1] + bias[n + 1];
        v.z = acc[mt][nt][2] + bias[n + 2];
        v.w = acc[mt][nt][3] + bias[n + 3];
        *(float4*)(Yf + (size_t)m * N + n) = v;
      } else {
        half4 hv;
#pragma unroll
        for (int r = 0; r < 4; ++r) hv[r] = (_Float16)(acc[mt][nt][r] * ysc);
        *(half4*)(Y + (size_t)m * N + n) = hv;
      }
    }
}

// ---------------------------------------------------------------------------
// V pretranspose: Vh[b][t][c] -> Vt packed per (b,h,kt) tile of 1024 els,
// STAGING-LINEAR layout (consumer lane `cell` reads its half8 pair linearly,
// so dense global_load_lds staging lands fragments conflict-free in LDS).
// ---------------------------------------------------------------------------
__global__ __launch_bounds__(256)
void transpose_v(const _Float16* __restrict__ Vh, _Float16* __restrict__ Vt) {
  constexpr int PAD = 1028;
  __shared__ _Float16 tile[16][PAD];
  const int b  = blockIdx.x >> 7;
  const int kt = blockIdx.x & 127;
  const int tid = threadIdx.x;

#pragma unroll
  for (int j = 0; j < 8; ++j) {
    const int ch = tid + 256 * j;
    const int t  = ch >> 7;
    const int c8 = ch & 127;
    *(half8*)&tile[t][c8 * 8] =
        *(const half8*)(Vh + ((size_t)b * T_ + kt * 16 + t) * C_ + c8 * 8);
  }
  __syncthreads();

#pragma unroll
  for (int j = 0; j < 8; ++j) {
    const int cc = tid + 256 * j;
    const int h  = cc >> 7;
    const int d  = (cc >> 1) & 63;
    const int th = (cc & 1) * 8;
    const int c  = h * 64 + d;
    half4 va, vb4;
#pragma unroll
    for (int i = 0; i < 4; ++i) va[i]  = tile[th + i][c];
#pragma unroll
    for (int i = 0; i < 4; ++i) vb4[i] = tile[th + 4 + i][c];
    const size_t tb = (((size_t)b * H_ + h) * 128 + kt) * 1024;
    const int nb = ((d >> 5) & 1) * 512 + ((th >> 2) * 16 + (d & 15)) * 8 +
                   ((d >> 4) & 1) * 4;
    *(half4*)(Vt + tb + nb) = va;
    *(half4*)(Vt + tb + nb + 128) = vb4;
  }
}

// ---------------------------------------------------------------------------
// MFMA head-softmax attention v14 = r9 champion (196us) + ONE change:
// single-barrier online softmax. r10's regression (196->262us) was scratch
// spill from its x2 unroll (FETCH/WRITE both +150-200MB, the spill
// signature) — NOT the single-barrier math (r4 tested it: neutral). So this
// version keeps r9 byte-identical (plain loop, STAGE(j) lambda with its
// address math, same STAGE placement right after the barrier) and only:
//   - computes local max mw, exps AGAINST mw, and local sum ps all BEFORE
//     one lds_barrier (was: write max / bar / read max / exp / write sum /
//     bar / read sum — two barriers, exps on the critical path);
//   - combine rescales: gm = max_i m_i; t = sum_i ps_i*exp(m_i-gm);
//     f = exp(mw-gm)/t; pf = s*f.  (exp(s-mw)*exp(mw-gm) == exp(s-gm).)
// Races: redm/reds single-buffer safe (top-syncthreads separates read(j)
// from write(j+1)); sK restage safe (all K ds_reads precede the lgkm
// barrier); sV ping-pong unchanged.
// LDS: sK 32KB + sV 64KB + redm/reds 32KB = 128KB; 1 block/CU.
// Q arrives pre-scaled by sqrt(D)=8 (folded into the projection).
// ---------------------------------------------------------------------------
__global__ __launch_bounds__(1024, 4)
void attn_mfma(const _Float16* __restrict__ Qhp, const _Float16* __restrict__ Khp,
               const _Float16* __restrict__ Vtp, _Float16* __restrict__ OP,
               int nsplit) {
  __shared__ _Float16 sK[16 * 1024];     // 32KB, row-XOR-swizzled
  __shared__ _Float16 sV[2][16][1024];   // 64KB, staging-linear, dbuf
  __shared__ f32x4 redm[4][4][64];       // 16KB [wg][qt][cell]
  __shared__ f32x4 reds[4][4][64];       // 16KB

  const int tid  = threadIdx.x;
  const int lane = tid & 63;
  const int w    = tid >> 6;             // 0..15
  const int qt   = w >> 2;               // q-subtile 0..3
  const int wg   = w & 3;                // head group 0..3
  const int l15  = lane & 15;
  const int quad = lane >> 4;
  const int cell = quad * 16 + l15;      // == lane

  const int nbq   = B_ * (T_ / 64);      // 64
  const int split = blockIdx.x / nbq;
  const int bq    = blockIdx.x % nbq;
  const int b  = bq >> 5;
  const int q0 = (bq & 31) << 6;

  // Q fragments (loop-invariant): rows q0+qt*16+l15, heads wg*4+hl
  const size_t qrow = ((size_t)b * T_ + q0 + qt * 16 + l15) * C_;
  half8 qh[4][2];
#pragma unroll
  for (int hl = 0; hl < 4; ++hl)
#pragma unroll
    for (int kk = 0; kk < 2; ++kk)
      qh[hl][kk] = *(const half8*)(Qhp + qrow + (wg * 4 + hl) * 64 + kk * 32 + quad * 8);

  f32x4 oacc[4][4];
#pragma unroll
  for (int hl = 0; hl < 4; ++hl)
#pragma unroll
    for (int mt = 0; mt < 4; ++mt)
      oacc[hl][mt] = (f32x4){0.f, 0.f, 0.f, 0.f};

  const int kpb  = T_ / nsplit;          // 512
  const int k_lo = split * kpb;
  const int jt   = kpb / 16;             // 32

  // staging: wave w stages K row w (XOR-swizzled source) + V head w (linear)
  const int kx  = (lane * 8) ^ ((w & 7) << 3);   // element offset, swizzled
  const _Float16* vhead = Vtp + ((size_t)b * H_ + w) * (128 * 1024);

  auto STAGE = [&](int j) {
    const int k0 = k_lo + j * 16;
    const size_t kr = ((size_t)b * T_ + k0 + w) * C_;
    gload16(Khp + kr + kx,       &sK[w * 1024]);
    gload16(Khp + kr + 512 + kx, &sK[w * 1024 + 512]);
    const _Float16* vsrc = vhead + (size_t)(k0 >> 4) * 1024;
    gload16(vsrc + lane * 8,       &sV[j & 1][w][0]);
    gload16(vsrc + lane * 8 + 512, &sV[j & 1][w][512]);
  };

  const int rsw   = (l15 & 7) << 3;      // K read-side swizzle (elements)
  const int hbase = wg * 256;

  STAGE(0);
  for (int j = 0; j < jt; ++j) {
    const int p = j & 1;
    __syncthreads();                     // drains staging vmcnt; tile visible

    // K fragments from LDS + QK^T (Q pre-scaled by sqrt(D))
    half8 akh[4][2];
#pragma unroll
    for (int hl = 0; hl < 4; ++hl)
#pragma unroll
      for (int kk = 0; kk < 2; ++kk)
        akh[hl][kk] = *(const half8*)&sK[l15 * 1024 +
            ((hbase + hl * 64 + kk * 32 + quad * 8) ^ rsw)];

    f32x4 s[4];
#pragma unroll
    for (int hl = 0; hl < 4; ++hl) s[hl] = (f32x4){0.f, 0.f, 0.f, 0.f};
#pragma unroll
    for (int hl = 0; hl < 4; ++hl)
#pragma unroll
      for (int kk = 0; kk < 2; ++kk)
        s[hl] = __builtin_amdgcn_mfma_f32_16x16x32_f16(akh[hl][kk], qh[hl][kk], s[hl], 0, 0, 0);

    // local (4-head) max + exp + local sum, all BEFORE the single barrier
    const f32x4 mw = vmax4(vmax4(s[0], s[1]), vmax4(s[2], s[3]));
    redm[wg][qt][cell] = mw;
    f32x4 ps = (f32x4){0.f, 0.f, 0.f, 0.f};
#pragma unroll
    for (int hl = 0; hl < 4; ++hl)
#pragma unroll
      for (int r = 0; r < 4; ++r) {
        const float ev = __expf(s[hl][r] - mw[r]);
        s[hl][r] = ev;                   // exp relative to LOCAL max
        ps[r] += ev;
      }
    reds[wg][qt][cell] = ps;
    lds_barrier();                       // the ONLY softmax barrier

    // all K reads complete block-wide -> safe to restage sK now
    if (j + 1 < jt) STAGE(j + 1);        // drain cover = combine + PV below

    // global max + rescaled global sum across the 4 head-group waves
    const f32x4 m0 = redm[0][qt][cell], m1 = redm[1][qt][cell];
    const f32x4 m2 = redm[2][qt][cell], m3 = redm[3][qt][cell];
    const f32x4 p0 = reds[0][qt][cell], p1 = reds[1][qt][cell];
    const f32x4 p2 = reds[2][qt][cell], p3 = reds[3][qt][cell];
    const f32x4 gm = vmax4(vmax4(m0, m1), vmax4(m2, m3));
    f32x4 f;
#pragma unroll
    for (int r = 0; r < 4; ++r) {
      const float t = p0[r] * __expf(m0[r] - gm[r]) + p1[r] * __expf(m1[r] - gm[r]) +
                      p2[r] * __expf(m2[r] - gm[r]) + p3[r] * __expf(m3[r] - gm[r]);
      f[r] = __expf(mw[r] - gm[r]) * __builtin_amdgcn_rcpf(t);
    }

    half4 pf[4];
#pragma unroll
    for (int hl = 0; hl < 4; ++hl)
#pragma unroll
      for (int r = 0; r < 4; ++r)
        pf[hl][r] = (_Float16)(s[hl][r] * f[r]);

    // V fragments (conflict-free linear reads) + PV
#pragma unroll
    for (int hl = 0; hl < 4; ++hl) {
      const half8 a0 = *(const half8*)&sV[p][wg * 4 + hl][cell * 8];
      const half8 a1 = *(const half8*)&sV[p][wg * 4 + hl][cell * 8 + 512];
      const half4 v0 = __builtin_shufflevector(a0, a0, 0, 1, 2, 3);
      const half4 v1 = __builtin_shufflevector(a0, a0, 4, 5, 6, 7);
      const half4 v2 = __builtin_shufflevector(a1, a1, 0, 1, 2, 3);
      const half4 v3 = __builtin_shufflevector(a1, a1, 4, 5, 6, 7);
      oacc[hl][0] = __builtin_amdgcn_mfma_f32_16x16x16f16(v0, pf[hl], oacc[hl][0], 0, 0, 0);
      oacc[hl][1] = __builtin_amdgcn_mfma_f32_16x16x16f16(v1, pf[hl], oacc[hl][1], 0, 0, 0);
      oacc[hl][2] = __builtin_amdgcn_mfma_f32_16x16x16f16(v2, pf[hl], oacc[hl][2], 0, 0, 0);
      oacc[hl][3] = __builtin_amdgcn_mfma_f32_16x16x16f16(v3, pf[hl], oacc[hl][3], 0, 0, 0);
    }
  }

  _Float16* op = OP + (size_t)split * ((size_t)B_ * T_ * C_);
  const size_t orow = ((size_t)b * T_ + q0 + qt * 16 + l15) * C_;
#pragma unroll
  for (int hl = 0; hl < 4; ++hl)
#pragma unroll
    for (int mt = 0; mt < 4; ++mt) {
      half4 hv;
#pragma unroll
      for (int r = 0; r < 4; ++r) hv[r] = (_Float16)oacc[hl][mt][r];
      *(half4*)(op + orow + (wg * 4 + hl) * 64 + mt * 16 + quad * 4) = hv;
    }
}

// ---------------------------------------------------------------------------
// AOh = (f16) sum over splits of f16 OP[s]  (fp32 accumulate)
// ---------------------------------------------------------------------------
__global__ __launch_bounds__(256)
void reduce_oh(const _Float16* __restrict__ OP, _Float16* __restrict__ AOh,
               int nsplit, size_t n) {
  const size_t i = ((size_t)blockIdx.x * 256 + threadIdx.x) * 8;
  float a[8] = {};
  for (int s = 0; s < nsplit; ++s) {
    const half8 v = *(const half8*)(OP + (size_t)s * n + i);
#pragma unroll
    for (int r = 0; r < 8; ++r) a[r] += (float)v[r];
  }
  half8 o;
#pragma unroll
  for (int r = 0; r < 8; ++r) o[r] = (_Float16)a[r];
  *(half8*)(AOh + i) = o;
}

}  // namespace

extern "C" void kernel_launch(void* const* d_in, const int* in_sizes, int n_in,
                              void* d_out, int out_size, void* d_ws, size_t ws_size,
                              hipStream_t stream) {
  const float* xq = (const float*)d_in[0];
  const float* xk = (const float*)d_in[1];
  const float* xv = (const float*)d_in[2];
  const float* Wq = (const float*)d_in[3];
  const float* Wk = (const float*)d_in[4];
  const float* Wv = (const float*)d_in[5];
  const float* Wo = (const float*)d_in[6];
  const float* bo = (const float*)d_in[7];
  float* out = (float*)d_out;

  const size_t MB   = 1ull << 20;
  const size_t nBTC = (size_t)B_ * T_ * C_;  // 4M elements

  char* wsb = (char*)d_ws;
  _Float16* Qh  = (_Float16*)(wsb + 0 * MB);
  _Float16* Kh  = (_Float16*)(wsb + 8 * MB);
  _Float16* Vt  = (_Float16*)(wsb + 16 * MB);
  _Float16* vh  = (_Float16*)(wsb + 24 * MB);
  _Float16* AOh = (_Float16*)(wsb + 24 * MB);
  _Float16* xqh = (_Float16*)(wsb + 32 * MB);
  _Float16* xkh = (_Float16*)(wsb + 40 * MB);
  _Float16* xvh = (_Float16*)(wsb + 48 * MB);
  _Float16* OP  = (_Float16*)(wsb + 32 * MB);
  _Float16* Wqh = (_Float16*)(wsb + 64 * MB);
  _Float16* Wkh = (_Float16*)(wsb + 66 * MB);
  _Float16* Wvh = (_Float16*)(wsb + 68 * MB);
  _Float16* Woh = (_Float16*)(wsb + 70 * MB);

  const int nsplit = 4;
  const int M = B_ * T_;                     // 4096
  dim3 blk(256);

  // 1) cast all 7 fp32 inputs to f16 (16M elements)
  cast7<<<dim3(8192), blk, 0, stream>>>(xq, xk, xv, Wq, Wk, Wv, Wo,
                                        xqh, xkh, xvh, Wqh, Wkh, Wvh, Woh);

  // 2) three projections, z-batched; Q pre-scaled by sqrt(D)=8 (quirk)
  gemm_f16nt<<<dim3(C_ / 128, M / 128, 3), blk, 0, stream>>>(
      xqh, xkh, xvh, Wqh, Wkh, Wvh, Qh, Kh, vh,
      nullptr, nullptr, C_, C_, 0, 8.f);

  // 3) V pretranspose (staging-linear fragment layout)
  transpose_v<<<dim3(B_ * 128), blk, 0, stream>>>(vh, Vt);

  // 4) fused head-softmax attention (QBLK=64, LDS-staged K/V, 1-barrier SM)
  attn_mfma<<<dim3(B_ * (T_ / 64) * nsplit), dim3(1024), 0, stream>>>(
      Qh, Kh, Vt, OP, nsplit);

  // 5) split reduction -> f16 AO
  reduce_oh<<<dim3((unsigned)(nBTC / 2048)), blk, 0, stream>>>(OP, AOh, nsplit, nBTC);

  // 6) output projection + bias -> fp32 out
  gemm_f16nt<<<dim3(C_ / 128, M / 128, 1), blk, 0, stream>>>(
      AOh, nullptr, nullptr, Woh, nullptr, nullptr, nullptr, nullptr, nullptr,
      out, bo, C_, C_, 2, 1.f);
}

// Round 12
// 358.134 us; speedup vs baseline: 1.3221x; 1.3221x over previous
//
#include <hip/hip_runtime.h>
#include <cmath>

namespace {

constexpr int B_ = 2;
constexpr int T_ = 2048;
constexpr int C_ = 1024;
constexpr int H_ = 16;
constexpr int D_ = 64;

typedef _Float16 half8 __attribute__((ext_vector_type(8)));
typedef _Float16 half4 __attribute__((ext_vector_type(4)));
typedef float f32x4 __attribute__((ext_vector_type(4)));

__device__ inline f32x4 vmax4(f32x4 a, f32x4 b) {
  f32x4 r;
  r[0] = fmaxf(a[0], b[0]); r[1] = fmaxf(a[1], b[1]);
  r[2] = fmaxf(a[2], b[2]); r[3] = fmaxf(a[3], b[3]);
  return r;
}

__device__ __forceinline__ void gload16(const _Float16* g, _Float16* l) {
  __builtin_amdgcn_global_load_lds(
      (const __attribute__((address_space(1))) unsigned int*)g,
      (__attribute__((address_space(3))) unsigned int*)l, 16, 0, 0);
}

// LDS-visibility barrier WITHOUT the vmcnt drain of __syncthreads():
// keeps in-flight global_load_lds staging alive across the barrier (T4).
__device__ __forceinline__ void lds_barrier() {
  asm volatile("s_waitcnt lgkmcnt(0)" ::: "memory");
  __builtin_amdgcn_s_barrier();
}

// ---------------------------------------------------------------------------
// Fused cast: 7 fp32 arrays -> f16 (xq,xk,xv: 4M els; Wq,Wk,Wv,Wo: 1M els).
// ---------------------------------------------------------------------------
__global__ __launch_bounds__(256)
void cast7(const float* __restrict__ xq, const float* __restrict__ xk,
           const float* __restrict__ xv, const float* __restrict__ wq,
           const float* __restrict__ wk, const float* __restrict__ wv,
           const float* __restrict__ wo,
           _Float16* __restrict__ dxq, _Float16* __restrict__ dxk,
           _Float16* __restrict__ dxv, _Float16* __restrict__ dwq,
           _Float16* __restrict__ dwk, _Float16* __restrict__ dwv,
           _Float16* __restrict__ dwo) {
  constexpr size_t NX = (size_t)4 << 20;
  constexpr size_t NW = (size_t)1 << 20;
  size_t g = ((size_t)blockIdx.x * 256 + threadIdx.x) * 8;
  const float* s; _Float16* d; size_t off;
  if      (g <     NX)          { s = xq; d = dxq; off = g; }
  else if (g < 2 * NX)          { s = xk; d = dxk; off = g - NX; }
  else if (g < 3 * NX)          { s = xv; d = dxv; off = g - 2 * NX; }
  else if (g < 3 * NX + NW)     { s = wq; d = dwq; off = g - 3 * NX; }
  else if (g < 3 * NX + 2 * NW) { s = wk; d = dwk; off = g - 3 * NX - NW; }
  else if (g < 3 * NX + 3 * NW) { s = wv; d = dwv; off = g - 3 * NX - 2 * NW; }
  else                          { s = wo; d = dwo; off = g - 3 * NX - 3 * NW; }
  const float4 a = *(const float4*)(s + off);
  const float4 b = *(const float4*)(s + off + 4);
  half8 h;
  h[0] = (_Float16)a.x; h[1] = (_Float16)a.y; h[2] = (_Float16)a.z; h[3] = (_Float16)a.w;
  h[4] = (_Float16)b.x; h[5] = (_Float16)b.y; h[6] = (_Float16)b.z; h[7] = (_Float16)b.w;
  *(half8*)(d + off) = h;
}

// ---------------------------------------------------------------------------
// LDS-staged f16 NT GEMM (m97 structure): Y[m][n] = sum_k A[m][k]*W[n][k].
// Tile 128x128, BK=32; 4 waves, each a 64x64 quadrant (4x4 16x16x32 MFMAs).
// mode 0: f16 Y out (z==0 output scaled by qsc: folds sqrt(D) into Q).
// mode 2: fp32 out + bias.
// ---------------------------------------------------------------------------
__global__ __launch_bounds__(256, 3)
void gemm_f16nt(const _Float16* __restrict__ A0, const _Float16* __restrict__ A1,
                const _Float16* __restrict__ A2,
                const _Float16* __restrict__ W0, const _Float16* __restrict__ W1,
                const _Float16* __restrict__ W2,
                _Float16* __restrict__ Y0, _Float16* __restrict__ Y1,
                _Float16* __restrict__ Y2,
                float* __restrict__ Yf, const float* __restrict__ bias,
                int K, int N, int mode, float qsc) {
  __shared__ _Float16 sA[128 * 32];
  __shared__ _Float16 sW[128 * 32];

  const int tid  = threadIdx.x;
  const int lane = tid & 63;
  const int w    = tid >> 6;
  const int l15  = lane & 15;
  const int quad = lane >> 4;
  const int z    = blockIdx.z;
  const _Float16* A = (z == 0) ? A0 : (z == 1) ? A1 : A2;
  const _Float16* W = (z == 0) ? W0 : (z == 1) ? W1 : W2;
  _Float16*       Y = (z == 0) ? Y0 : (z == 1) ? Y1 : Y2;

  const int m0 = blockIdx.y * 128;
  const int n0 = blockIdx.x * 128;

  const int Rb  = lane >> 2;
  const int pch = lane & 3;
  const int lch = pch ^ ((Rb >> 1) & 3);
  const int swr = (l15 >> 1) & 3;

  f32x4 acc[4][4];
#pragma unroll
  for (int mt = 0; mt < 4; ++mt)
#pragma unroll
    for (int nt = 0; nt < 4; ++nt)
      acc[mt][nt] = (f32x4){0.f, 0.f, 0.f, 0.f};

  const int wm = (w >> 1) * 64;
  const int wn = (w & 1) * 64;

  for (int k0 = 0; k0 < K; k0 += 32) {
    __syncthreads();
#pragma unroll
    for (int j = 0; j < 2; ++j) {
      const int seg = w * 32 + j * 16;
      gload16(A + (size_t)(m0 + seg + Rb) * K + k0 + lch * 8, &sA[seg * 32]);
      gload16(W + (size_t)(n0 + seg + Rb) * K + k0 + lch * 8, &sW[seg * 32]);
    }
    __syncthreads();

    half8 af[4], wf[4];
#pragma unroll
    for (int mt = 0; mt < 4; ++mt) {
      const int R = wm + mt * 16 + l15;
      af[mt] = *(const half8*)&sA[R * 32 + (quad ^ swr) * 8];
    }
#pragma unroll
    for (int nt = 0; nt < 4; ++nt) {
      const int R = wn + nt * 16 + l15;
      wf[nt] = *(const half8*)&sW[R * 32 + (quad ^ swr) * 8];
    }
#pragma unroll
    for (int mt = 0; mt < 4; ++mt)
#pragma unroll
      for (int nt = 0; nt < 4; ++nt)
        acc[mt][nt] = __builtin_amdgcn_mfma_f32_16x16x32_f16(wf[nt], af[mt], acc[mt][nt], 0, 0, 0);
  }

  const float ysc = (mode == 0 && z == 0) ? qsc : 1.f;
#pragma unroll
  for (int mt = 0; mt < 4; ++mt)
#pragma unroll
    for (int nt = 0; nt < 4; ++nt) {
      const int m = m0 + wm + mt * 16 + l15;
      const int n = n0 + wn + nt * 16 + quad * 4;
      if (mode == 2) {
        float4 v;
        v.x = acc[mt][nt][0] + bias[n + 0];
        v.y = acc[mt][nt][1] + bias[n + 1];
        v.z = acc[mt][nt][2] + bias[n + 2];
        v.w = acc[mt][nt][3] + bias[n + 3];
        *(float4*)(Yf + (size_t)m * N + n) = v;
      } else {
        half4 hv;
#pragma unroll
        for (int r = 0; r < 4; ++r) hv[r] = (_Float16)(acc[mt][nt][r] * ysc);
        *(half4*)(Y + (size_t)m * N + n) = hv;
      }
    }
}

// ---------------------------------------------------------------------------
// V pretranspose: Vh[b][t][c] -> Vt packed per (b,h,kt) tile of 1024 els,
// STAGING-LINEAR layout (consumer lane `cell` reads its half8 pair linearly,
// so dense global_load_lds staging lands fragments conflict-free in LDS).
// ---------------------------------------------------------------------------
__global__ __launch_bounds__(256)
void transpose_v(const _Float16* __restrict__ Vh, _Float16* __restrict__ Vt) {
  constexpr int PAD = 1028;
  __shared__ _Float16 tile[16][PAD];
  const int b  = blockIdx.x >> 7;
  const int kt = blockIdx.x & 127;
  const int tid = threadIdx.x;

#pragma unroll
  for (int j = 0; j < 8; ++j) {
    const int ch = tid + 256 * j;
    const int t  = ch >> 7;
    const int c8 = ch & 127;
    *(half8*)&tile[t][c8 * 8] =
        *(const half8*)(Vh + ((size_t)b * T_ + kt * 16 + t) * C_ + c8 * 8);
  }
  __syncthreads();

#pragma unroll
  for (int j = 0; j < 8; ++j) {
    const int cc = tid + 256 * j;
    const int h  = cc >> 7;
    const int d  = (cc >> 1) & 63;
    const int th = (cc & 1) * 8;
    const int c  = h * 64 + d;
    half4 va, vb4;
#pragma unroll
    for (int i = 0; i < 4; ++i) va[i]  = tile[th + i][c];
#pragma unroll
    for (int i = 0; i < 4; ++i) vb4[i] = tile[th + 4 + i][c];
    const size_t tb = (((size_t)b * H_ + h) * 128 + kt) * 1024;
    const int nb = ((d >> 5) & 1) * 512 + ((th >> 2) * 16 + (d & 15)) * 8 +
                   ((d >> 4) & 1) * 4;
    *(half4*)(Vt + tb + nb) = va;
    *(half4*)(Vt + tb + nb + 128) = vb4;
  }
}

// ---------------------------------------------------------------------------
// MFMA head-softmax attention v15 = r9 champion (196us) VERBATIM + ONE
// change: XCD-pinned (b,split) mapping.
// r10 (unroll x2) and r11 (single-barrier SM) both regressed from r9 with
// the same signature: FETCH_SIZE (TCC L2-miss traffic) inflated 277MB ->
// 479/843MB and time tracked traffic. Lesson: this structure IS sensitive
// to L2-miss traffic. So: revert the softmax to r9's two-phase form and
// attack r9's own 277MB instead. Each (b,split) slice = 2MB K + 1MB V
// < 4MB per-XCD L2. Grid = 256 = 1 block/CU = 32 blocks/XCD; hardware
// round-robins blockIdx over XCDs, so (b,split) = blockIdx&7 gives every
// XCD exactly ONE slice, L2-resident for the whole kernel (r3 measured
// this map: FETCH /3, no cost).
// Everything else (staging, barriers, reductions, PV) is r9 byte-identical.
// Q arrives pre-scaled by sqrt(D)=8 (folded into the projection).
// ---------------------------------------------------------------------------
__global__ __launch_bounds__(1024, 4)
void attn_mfma(const _Float16* __restrict__ Qhp, const _Float16* __restrict__ Khp,
               const _Float16* __restrict__ Vtp, _Float16* __restrict__ OP,
               int nsplit) {
  __shared__ _Float16 sK[16 * 1024];     // 32KB, row-XOR-swizzled
  __shared__ _Float16 sV[2][16][1024];   // 64KB, staging-linear, dbuf
  __shared__ f32x4 redm[4][4][64];       // 16KB [wg][qt][cell]
  __shared__ f32x4 reds[4][4][64];       // 16KB

  const int tid  = threadIdx.x;
  const int lane = tid & 63;
  const int w    = tid >> 6;             // 0..15
  const int qt   = w >> 2;               // q-subtile 0..3
  const int wg   = w & 3;                // head group 0..3
  const int l15  = lane & 15;
  const int quad = lane >> 4;
  const int cell = quad * 16 + l15;      // == lane

  // XCD-pinned mapping: xcd = blockIdx&7 selects (b, split); all 32 blocks
  // resident on one XCD stream the SAME 3MB K/V slice (fits 4MB L2).
  const int xcd   = blockIdx.x & 7;
  const int qi    = blockIdx.x >> 3;     // 0..31
  const int b     = xcd & 1;
  const int split = xcd >> 1;            // 0..3
  const int q0    = qi << 6;

  // Q fragments (loop-invariant): rows q0+qt*16+l15, heads wg*4+hl
  const size_t qrow = ((size_t)b * T_ + q0 + qt * 16 + l15) * C_;
  half8 qh[4][2];
#pragma unroll
  for (int hl = 0; hl < 4; ++hl)
#pragma unroll
    for (int kk = 0; kk < 2; ++kk)
      qh[hl][kk] = *(const half8*)(Qhp + qrow + (wg * 4 + hl) * 64 + kk * 32 + quad * 8);

  f32x4 oacc[4][4];
#pragma unroll
  for (int hl = 0; hl < 4; ++hl)
#pragma unroll
    for (int mt = 0; mt < 4; ++mt)
      oacc[hl][mt] = (f32x4){0.f, 0.f, 0.f, 0.f};

  const int kpb  = T_ / nsplit;          // 512
  const int k_lo = split * kpb;
  const int jt   = kpb / 16;             // 32

  // staging: wave w stages K row w (XOR-swizzled source) + V head w (linear)
  const int kx  = (lane * 8) ^ ((w & 7) << 3);   // element offset, swizzled
  const _Float16* vhead = Vtp + ((size_t)b * H_ + w) * (128 * 1024);

  auto STAGE = [&](int j) {
    const int k0 = k_lo + j * 16;
    const size_t kr = ((size_t)b * T_ + k0 + w) * C_;
    gload16(Khp + kr + kx,       &sK[w * 1024]);
    gload16(Khp + kr + 512 + kx, &sK[w * 1024 + 512]);
    const _Float16* vsrc = vhead + (size_t)(k0 >> 4) * 1024;
    gload16(vsrc + lane * 8,       &sV[j & 1][w][0]);
    gload16(vsrc + lane * 8 + 512, &sV[j & 1][w][512]);
  };

  const int rsw   = (l15 & 7) << 3;      // K read-side swizzle (elements)
  const int hbase = wg * 256;

  STAGE(0);
  for (int j = 0; j < jt; ++j) {
    const int p = j & 1;
    __syncthreads();                     // drains staging vmcnt; tile visible

    // K fragments from LDS + QK^T (Q pre-scaled by sqrt(D))
    half8 akh[4][2];
#pragma unroll
    for (int hl = 0; hl < 4; ++hl)
#pragma unroll
      for (int kk = 0; kk < 2; ++kk)
        akh[hl][kk] = *(const half8*)&sK[l15 * 1024 +
            ((hbase + hl * 64 + kk * 32 + quad * 8) ^ rsw)];

    f32x4 s[4];
#pragma unroll
    for (int hl = 0; hl < 4; ++hl) s[hl] = (f32x4){0.f, 0.f, 0.f, 0.f};
#pragma unroll
    for (int hl = 0; hl < 4; ++hl)
#pragma unroll
      for (int kk = 0; kk < 2; ++kk)
        s[hl] = __builtin_amdgcn_mfma_f32_16x16x32_f16(akh[hl][kk], qh[hl][kk], s[hl], 0, 0, 0);

    // head-softmax phase 1: local (4-head) max
    redm[wg][qt][cell] = vmax4(vmax4(s[0], s[1]), vmax4(s[2], s[3]));
    lds_barrier();                       // barA (no vmcnt drain)

    if (j + 1 < jt) STAGE(j + 1);        // K(j) reads done (barA); V -> other buf

    const f32x4 gmax = vmax4(vmax4(redm[0][qt][cell], redm[1][qt][cell]),
                             vmax4(redm[2][qt][cell], redm[3][qt][cell]));
    f32x4 ps = (f32x4){0.f, 0.f, 0.f, 0.f};
#pragma unroll
    for (int hl = 0; hl < 4; ++hl)
#pragma unroll
      for (int r = 0; r < 4; ++r) {
        const float ev = __expf(s[hl][r] - gmax[r]);
        s[hl][r] = ev;
        ps[r] += ev;
      }
    reds[wg][qt][cell] = ps;
    lds_barrier();                       // barB (staging stays in flight)

    const f32x4 gs = reds[0][qt][cell] + reds[1][qt][cell] +
                     reds[2][qt][cell] + reds[3][qt][cell];
    f32x4 inv;
#pragma unroll
    for (int r = 0; r < 4; ++r) inv[r] = __builtin_amdgcn_rcpf(gs[r]);

    half4 pf[4];
#pragma unroll
    for (int hl = 0; hl < 4; ++hl)
#pragma unroll
      for (int r = 0; r < 4; ++r)
        pf[hl][r] = (_Float16)(s[hl][r] * inv[r]);

    // V fragments (conflict-free linear reads) + PV
#pragma unroll
    for (int hl = 0; hl < 4; ++hl) {
      const half8 a0 = *(const half8*)&sV[p][wg * 4 + hl][cell * 8];
      const half8 a1 = *(const half8*)&sV[p][wg * 4 + hl][cell * 8 + 512];
      const half4 v0 = __builtin_shufflevector(a0, a0, 0, 1, 2, 3);
      const half4 v1 = __builtin_shufflevector(a0, a0, 4, 5, 6, 7);
      const half4 v2 = __builtin_shufflevector(a1, a1, 0, 1, 2, 3);
      const half4 v3 = __builtin_shufflevector(a1, a1, 4, 5, 6, 7);
      oacc[hl][0] = __builtin_amdgcn_mfma_f32_16x16x16f16(v0, pf[hl], oacc[hl][0], 0, 0, 0);
      oacc[hl][1] = __builtin_amdgcn_mfma_f32_16x16x16f16(v1, pf[hl], oacc[hl][1], 0, 0, 0);
      oacc[hl][2] = __builtin_amdgcn_mfma_f32_16x16x16f16(v2, pf[hl], oacc[hl][2], 0, 0, 0);
      oacc[hl][3] = __builtin_amdgcn_mfma_f32_16x16x16f16(v3, pf[hl], oacc[hl][3], 0, 0, 0);
    }
  }

  _Float16* op = OP + (size_t)split * ((size_t)B_ * T_ * C_);
  const size_t orow = ((size_t)b * T_ + q0 + qt * 16 + l15) * C_;
#pragma unroll
  for (int hl = 0; hl < 4; ++hl)
#pragma unroll
    for (int mt = 0; mt < 4; ++mt) {
      half4 hv;
#pragma unroll
      for (int r = 0; r < 4; ++r) hv[r] = (_Float16)oacc[hl][mt][r];
      *(half4*)(op + orow + (wg * 4 + hl) * 64 + mt * 16 + quad * 4) = hv;
    }
}

// ---------------------------------------------------------------------------
// AOh = (f16) sum over splits of f16 OP[s]  (fp32 accumulate)
// ---------------------------------------------------------------------------
__global__ __launch_bounds__(256)
void reduce_oh(const _Float16* __restrict__ OP, _Float16* __restrict__ AOh,
               int nsplit, size_t n) {
  const size_t i = ((size_t)blockIdx.x * 256 + threadIdx.x) * 8;
  float a[8] = {};
  for (int s = 0; s < nsplit; ++s) {
    const half8 v = *(const half8*)(OP + (size_t)s * n + i);
#pragma unroll
    for (int r = 0; r < 8; ++r) a[r] += (float)v[r];
  }
  half8 o;
#pragma unroll
  for (int r = 0; r < 8; ++r) o[r] = (_Float16)a[r];
  *(half8*)(AOh + i) = o;
}

}  // namespace

extern "C" void kernel_launch(void* const* d_in, const int* in_sizes, int n_in,
                              void* d_out, int out_size, void* d_ws, size_t ws_size,
                              hipStream_t stream) {
  const float* xq = (const float*)d_in[0];
  const float* xk = (const float*)d_in[1];
  const float* xv = (const float*)d_in[2];
  const float* Wq = (const float*)d_in[3];
  const float* Wk = (const float*)d_in[4];
  const float* Wv = (const float*)d_in[5];
  const float* Wo = (const float*)d_in[6];
  const float* bo = (const float*)d_in[7];
  float* out = (float*)d_out;

  const size_t MB   = 1ull << 20;
  const size_t nBTC = (size_t)B_ * T_ * C_;  // 4M elements

  char* wsb = (char*)d_ws;
  _Float16* Qh  = (_Float16*)(wsb + 0 * MB);
  _Float16* Kh  = (_Float16*)(wsb + 8 * MB);
  _Float16* Vt  = (_Float16*)(wsb + 16 * MB);
  _Float16* vh  = (_Float16*)(wsb + 24 * MB);
  _Float16* AOh = (_Float16*)(wsb + 24 * MB);
  _Float16* xqh = (_Float16*)(wsb + 32 * MB);
  _Float16* xkh = (_Float16*)(wsb + 40 * MB);
  _Float16* xvh = (_Float16*)(wsb + 48 * MB);
  _Float16* OP  = (_Float16*)(wsb + 32 * MB);
  _Float16* Wqh = (_Float16*)(wsb + 64 * MB);
  _Float16* Wkh = (_Float16*)(wsb + 66 * MB);
  _Float16* Wvh = (_Float16*)(wsb + 68 * MB);
  _Float16* Woh = (_Float16*)(wsb + 70 * MB);

  const int nsplit = 4;
  const int M = B_ * T_;                     // 4096
  dim3 blk(256);

  // 1) cast all 7 fp32 inputs to f16 (16M elements)
  cast7<<<dim3(8192), blk, 0, stream>>>(xq, xk, xv, Wq, Wk, Wv, Wo,
                                        xqh, xkh, xvh, Wqh, Wkh, Wvh, Woh);

  // 2) three projections, z-batched; Q pre-scaled by sqrt(D)=8 (quirk)
  gemm_f16nt<<<dim3(C_ / 128, M / 128, 3), blk, 0, stream>>>(
      xqh, xkh, xvh, Wqh, Wkh, Wvh, Qh, Kh, vh,
      nullptr, nullptr, C_, C_, 0, 8.f);

  // 3) V pretranspose (staging-linear fragment layout)
  transpose_v<<<dim3(B_ * 128), blk, 0, stream>>>(vh, Vt);

  // 4) fused head-softmax attention (r9 structure, XCD-pinned slices)
  attn_mfma<<<dim3(B_ * (T_ / 64) * nsplit), dim3(1024), 0, stream>>>(
      Qh, Kh, Vt, OP, nsplit);

  // 5) split reduction -> f16 AO
  reduce_oh<<<dim3((unsigned)(nBTC / 2048)), blk, 0, stream>>>(OP, AOh, nsplit, nBTC);

  // 6) output projection + bias -> fp32 out
  gemm_f16nt<<<dim3(C_ / 128, M / 128, 1), blk, 0, stream>>>(
      AOh, nullptr, nullptr, Woh, nullptr, nullptr, nullptr, nullptr, nullptr,
      out, bo, C_, C_, 2, 1.f);
}